// Round 3
// baseline (276.611 us; speedup 1.0000x reference)
//
#include <hip/hip_runtime.h>

#define DEVFN __device__ __forceinline__

typedef __attribute__((ext_vector_type(8))) short short8;
typedef __attribute__((ext_vector_type(4))) float floatx4;
typedef unsigned short u16;
typedef unsigned int u32;

typedef __attribute__((address_space(1))) const void gas_void;
typedef __attribute__((address_space(3))) void las_void;

constexpr int B_   = 2;
constexpr int CIN  = 16;
constexpr int COUT = 16;
constexpr int T_   = 31;
constexpr int H_   = 128;
constexpr int W_   = 128;
constexpr int OC   = 6 * COUT;   // 96
constexpr int HW   = H_ * W_;    // 16384
constexpr int KVOL = CIN * 27;   // 432
constexpr int KP   = 448;        // K padded to 14 * 32

// padded x layout [b][TP][HP][WP][16ci], fp16
constexpr int TP = T_ + 2;       // 33
constexpr int HP = H_ + 2;       // 130
constexpr int WP = W_ + 2;       // 130
constexpr int Sh = WP * 16;      // elems per hh step
constexpr int St = HP * Sh;      // elems per tt step
constexpr int NPAD  = B_ * TP * HP * WP;   // 1,115,400 positions
// +1 zeroed t-slab: fused kernel's pad column t=31 reads padded tt up to 33.
constexpr int NPADX = NPAD + HP * WP;      // 1,132,300
constexpr int PADBLK = (NPADX + 255) / 256;
constexpr int WBLK   = (OC * KP + 255) / 256;

// A-in-LDS: one phase = 7 k-steps, layout [sl(7)][m(6)][quad(4)][n(16)][j(8)]
constexpr int APH = 7 * 6 * 4 * 16 * 8;  // 21504 elems = 43008 B per phase

// x-tile in LDS: 34 t' x 3 h' x (10 w x 16 ci) strips of 320 B, chunked as
// 16B units. Chunk c -> strip c/20, 16B-offset c%20; LDS addr = c*16 B
// (linear -> global_load_lds-compatible). Padded to 2048 chunks.
constexpr int XCHUNK = 34 * 3 * 20;   // 2040 real chunks
constexpr int XT_OFF = APH;           // u16 elems (byte 43008)
constexpr int XT_U16 = 2048 * 8;      // 16384 u16 = 32768 B
constexpr int LDS_U16 = APH + XT_U16; // 37888 u16 = 75776 B -> 2 blocks/CU

// gates-in-LDS (aliases A/x-tile after conv): [g(6)][c(16)][t*8+w],
// c-stride padded 264 -> 268 elems for bank spread.
constexpr int GSTR = 268;
constexpr int GS   = 16 * GSTR;   // 4288
constexpr int GLDS = 6 * GS;      // 25728 elems = 51456 B  (< LDS_U16)

DEVFN float sigmoid_(float v) { return 1.f / (1.f + __expf(-v)); }
DEVFN float tanh_(float v)    { return 1.f - 2.f / (__expf(2.f * v) + 1.f); }

DEVFN u16 f2h(float v) {  // RNE f32 -> fp16 raw bits
  _Float16 h = (_Float16)v;
  u16 u; __builtin_memcpy(&u, &h, 2); return u;
}
DEVFN float h2f(u16 u) {
  _Float16 h; __builtin_memcpy(&h, &u, 2); return (float)h;
}

// ---------------------------------------------------------------------------
// Prep (merged): blocks [0, PADBLK) do x fp32->fp16 pad/transpose; blocks
// [PADBLK, PADBLK+WBLK) reorder weights to the LDS-ready layout.
// ---------------------------------------------------------------------------
__global__ __launch_bounds__(256) void prep_kernel(const float* __restrict__ x,
                                                   const float* __restrict__ cw,
                                                   u16* __restrict__ xh,
                                                   u16* __restrict__ wr) {
  if (blockIdx.x < PADBLK) {
    const int idx = blockIdx.x * 256 + threadIdx.x;
    if (idx >= NPADX) return;
    int r = idx;
    const int ww = r % WP; r /= WP;
    const int hh = r % HP; r /= HP;
    const int tt = r % TP; const int b = r / TP;
    const bool in_ = (b < B_) & (tt >= 1) & (tt <= T_) & (hh >= 1) &
                     (hh <= H_) & (ww >= 1) & (ww <= W_);
    const int ts = in_ ? tt - 1 : 0, hs = in_ ? hh - 1 : 0,
              ws = in_ ? ww - 1 : 0;
    const int bs = in_ ? b : 0;
    const float* xp = x + ((size_t)bs * CIN * T_ + ts) * HW + hs * W_ + ws;
    u32 ph[8];
#pragma unroll
    for (int ci = 0; ci < 16; ++ci) {
      const float v = in_ ? xp[ci * (T_ * HW)] : 0.f;
      const u16 hu = f2h(v);
      if (ci & 1) ph[ci >> 1] |= ((u32)hu) << 16;
      else        ph[ci >> 1] = hu;
    }
    uint4* dh = (uint4*)(xh + (size_t)idx * 16);
    dh[0] = make_uint4(ph[0], ph[1], ph[2], ph[3]);
    dh[1] = make_uint4(ph[4], ph[5], ph[6], ph[7]);
  } else {
    // weights [oc][ci][27] fp32 -> [s(14)][m(6)][quad(4)][n(16)][j(8)] fp16,
    // oc = m*16+n, k = s*32+quad*8+j.
    const int idx = (blockIdx.x - PADBLK) * 256 + threadIdx.x;
    if (idx >= OC * KP) return;
    const int j    = idx & 7;
    const int n    = (idx >> 3) & 15;
    const int quad = (idx >> 7) & 3;
    const int m    = (idx >> 9) % 6;
    const int s    = idx / 3072;
    const int oc   = m * 16 + n;
    const int k    = s * 32 + quad * 8 + j;
    const int off  = k >> 4, ci = k & 15;
    const float v  = (off < 27) ? cw[oc * KVOL + ci * 27 + off] : 0.f;
    wr[idx] = f2h(v);
  }
}

// ---------------------------------------------------------------------------
// One k-phase (7 steps). B now comes from the LDS x-tile: byte offset
// dL(tap) = kd*960 + kh*320 + kw*32 is compile-time (fits the DS imm);
// per-thread tile bases bb[j] fold t(j), w, cihalf. 10 ds_read_b128 + 24
// MFMA per step, zero per-step address VALU beyond one cndmask+add.
// ---------------------------------------------------------------------------
template <int PH>
DEVFN void kphase(const u16* __restrict__ As, const u16* __restrict__ xt,
                  const int (&bb)[4], int n, int quad, int qhalf,
                  floatx4 (&acc)[6][4]) {
#pragma unroll
  for (int sl = 0; sl < 7; ++sl) {
    const int s  = PH * 7 + sl;
    const int oE = 2 * s;
    const int oO = (2 * s + 1 < 27) ? (2 * s + 1) : 26;  // K-pad clamp (A=0)
    const int dE = (oE / 9) * 960 + ((oE % 9) / 3) * 320 + (oE % 3) * 32;
    const int dO = (oO / 9) * 960 + ((oO % 9) / 3) * 320 + (oO % 3) * 32;
    const int d  = qhalf ? dO : dE;  // bytes into x-tile
    short8 bh[4];
#pragma unroll
    for (int j = 0; j < 4; ++j)
      bh[j] = *(const short8*)((const char*)xt + (bb[j] + d));
#pragma unroll
    for (int m = 0; m < 6; ++m) {
      const short8 a =
          *(const short8*)(As + (sl * 6 + m) * 512 + quad * 128 + n * 8);
#pragma unroll
      for (int j = 0; j < 4; ++j)
        acc[m][j] =
            __builtin_amdgcn_mfma_f32_16x16x32_f16(a, bh[j], acc[m][j], 0, 0, 0);
    }
  }
}

// ---------------------------------------------------------------------------
// Fused conv + bidirectional SRU scan.
// Block = 4 waves = one (b, h, 8w) tile covering ALL t (t-major columns):
//   t = wv*8 + j*2 + (n>>3), w = wbase + (n&7); t==31 is a discarded pad col.
// x-tile (34t' x 3h' x 10w x 16ci = 32.6 KB) staged ONCE into LDS via
// global_load_lds(16B) -> all 56 tap-loads become ds_read_b128 (kills the
// 940 MB L2/L3 over-read). A staged in 2 phases as before. Scan is split
// fwd/bwd with NO register state across barriers: both halves park their
// results as fp32 bits in dead gate planes, then all 256 threads combine.
// ---------------------------------------------------------------------------
__global__ __launch_bounds__(256, 2) void conv_sru_fused(
    const u16* __restrict__ xh, const u16* __restrict__ wr,
    const float* __restrict__ cb, float* __restrict__ out) {
  const int lane = threadIdx.x & 63, wv = threadIdx.x >> 6;
  const int n = lane & 15, quad = lane >> 4;
  const int qhalf = quad >> 1, cihalf = quad & 1;
  const int th = n >> 3, wloc = n & 7;
  const int wbase = blockIdx.x * 8;
  const int h = blockIdx.y;
  const int b = blockIdx.z;

  __shared__ __align__(16) u16 Ls[LDS_U16];  // 75776 B
  u16* As = Ls;               // A phase buffer (43008 B)
  u16* xt = Ls + XT_OFF;      // x-tile (32768 B)

  // ---- stage x-tile: 2048 16B chunks, linear LDS dest ----
  {
    const u16* xgb = xh + ((size_t)(b * TP) * HP + h) * WP * 16 +
                     (size_t)wbase * 16;
#pragma unroll
    for (int it = 0; it < 8; ++it) {
      const int cl = it * 256 + (int)threadIdx.x;   // linear dest chunk
      const int c = (cl < XCHUNK) ? cl : (XCHUNK - 1);  // clamp src only
      const int strip = c / 20;
      const int o16 = c - strip * 20;
      const int tt = strip / 3;
      const int hh = strip - tt * 3;
      const u16* src = xgb + (size_t)tt * St + hh * Sh + o16 * 8;
      __builtin_amdgcn_global_load_lds((gas_void*)src,
                                       (las_void*)(xt + (size_t)cl * 8), 16, 0,
                                       0);
    }
  }

  // per-thread x-tile byte bases for the 4 column tiles (j -> t += 2)
  int bb[4];
#pragma unroll
  for (int j = 0; j < 4; ++j)
    bb[j] = (wv * 8 + j * 2 + th) * 960 + wloc * 32 + cihalf * 16;

  floatx4 acc[6][4];
#pragma unroll
  for (int m = 0; m < 6; ++m)
#pragma unroll
    for (int j = 0; j < 4; ++j) acc[m][j] = (floatx4)(0.f);

  // phase 0: stage A[s=0..6], compute
  for (int i = threadIdx.x; i < APH / 8; i += 256)
    ((uint4*)As)[i] = ((const uint4*)wr)[i];
  __syncthreads();
  kphase<0>(As, xt, bb, n, quad, qhalf, acc);

  // phase 1: restage A[s=7..13], compute
  __syncthreads();
  for (int i = threadIdx.x; i < APH / 8; i += 256)
    ((uint4*)As)[i] = ((const uint4*)(wr + APH))[i];
  __syncthreads();
  kphase<1>(As, xt, bb, n, quad, qhalf, acc);

  // epilogue: bias + activation -> gates in LDS (overwrites A/x-tile)
  __syncthreads();
#pragma unroll
  for (int m = 0; m < 6; ++m) {
    const bool isTanh = (m == 0) || (m == 5);
#pragma unroll
    for (int rr = 0; rr < 4; ++rr) {
      const int c = quad * 4 + rr;
      const float bias = cb[m * 16 + c];
#pragma unroll
      for (int j = 0; j < 4; ++j) {
        const int t = wv * 8 + j * 2 + th;
        float v = acc[m][j][rr] + bias;
        v = isTanh ? tanh_(v) : sigmoid_(v);
        Ls[(m * 16 + c) * GSTR + t * 8 + wloc] = f2h(v);
      }
    }
  }
  __syncthreads();

  // ---- split bidirectional scan, no regs live across barriers ----
  const int tid  = threadIdx.x;
  const int half = tid >> 7;        // 0: forward (waves 0-1), 1: backward
  const int ser  = tid & 127;       // (c, w) series
  const int c = ser >> 3, w = ser & 7;
  const int gb = c * GSTR + w;

  if (half == 0) {
    // forward; htl stored as fp32 bits into dead f (plane1) / r (plane3)
    float C = 0.f;
#pragma unroll
    for (int t = 0; t < T_; ++t) {
      const float wx = h2f(Ls[0 * GS + gb + t * 8]);
      const float f  = h2f(Ls[1 * GS + gb + t * 8]);
      const float r  = h2f(Ls[3 * GS + gb + t * 8]);
      const float xv = h2f(Ls[5 * GS + gb + t * 8]);
      C = (t == 0) ? (1.f - f) : (f * C + (1.f - f) * wx);
      const float htl = r * C + (1.f - r) * xv;
      const u32 bits = __float_as_uint(htl);
      Ls[1 * GS + gb + t * 8] = (u16)(bits & 0xffffu);
      Ls[3 * GS + gb + t * 8] = (u16)(bits >> 16);
    }
  } else {
    // backward; htr stored as fp32 bits into dead f2 (plane2) / r2 (plane4)
    float C2 = 0.f;
#pragma unroll
    for (int t = T_ - 1; t >= 0; --t) {
      const float wx = h2f(Ls[0 * GS + gb + t * 8]);
      const float f2 = h2f(Ls[2 * GS + gb + t * 8]);
      const float r2 = h2f(Ls[4 * GS + gb + t * 8]);
      const float xv = h2f(Ls[5 * GS + gb + t * 8]);
      C2 = (t == T_ - 1) ? (1.f - f2) : (f2 * C2 + (1.f - f2) * wx);
      const float htr = r2 * C2 + (1.f - r2) * xv;
      const u32 bits = __float_as_uint(htr);
      Ls[2 * GS + gb + t * 8] = (u16)(bits & 0xffffu);
      Ls[4 * GS + gb + t * 8] = (u16)(bits >> 16);
    }
  }
  __syncthreads();

  // combine + store: all 256 threads, half0 t=0..15, half1 t=16..30
  {
    const int tlo = half ? 16 : 0;
    const int thi = half ? T_ : 16;
    const size_t ob = ((size_t)(b * COUT + c) * T_) * HW + h * W_ + wbase + w;
    for (int t = tlo; t < thi; ++t) {
      const u32 l1 = Ls[1 * GS + gb + t * 8];
      const u32 h1 = Ls[3 * GS + gb + t * 8];
      const u32 l2 = Ls[2 * GS + gb + t * 8];
      const u32 h2 = Ls[4 * GS + gb + t * 8];
      out[ob + (size_t)t * HW] =
          __uint_as_float(l1 | (h1 << 16)) + __uint_as_float(l2 | (h2 << 16));
    }
  }
}

// ---------------------------------------------------------------------------
// Fallback path (only if ws too small for the fused MFMA path).
// ---------------------------------------------------------------------------
__global__ __launch_bounds__(256) void sru_scan_kernel(
    const u16* __restrict__ g, float* __restrict__ out) {
  const int idx  = blockIdx.x * 256 + threadIdx.x;
  const int sp   = idx & (HW - 1);
  const int bc   = idx >> 14;
  const int base = bc * (T_ * HW) + sp;
  const int P    = B_ * COUT * T_ * HW;

  const u16* gWx = g + 0 * P + base;
  const u16* gF  = g + 1 * P + base;
  const u16* gF2 = g + 2 * P + base;
  const u16* gR  = g + 3 * P + base;
  const u16* gR2 = g + 4 * P + base;
  const u16* gX  = g + 5 * P + base;

  float wxs[T_], xs[T_], htl[T_];
  float C = 0.f;
#pragma unroll
  for (int t = 0; t < T_; ++t) {
    const float wx = h2f(gWx[t * HW]);
    const float f  = h2f(gF[t * HW]);
    const float r  = h2f(gR[t * HW]);
    const float xv = h2f(gX[t * HW]);
    wxs[t] = wx;
    xs[t]  = xv;
    C = (t == 0) ? (1.f - f) : (f * C + (1.f - f) * wx);
    htl[t] = r * C + (1.f - r) * xv;
  }
  float C2 = 0.f;
#pragma unroll
  for (int t = T_ - 1; t >= 0; --t) {
    const float f2 = h2f(gF2[t * HW]);
    const float r2 = h2f(gR2[t * HW]);
    C2 = (t == T_ - 1) ? (1.f - f2) : (f2 * C2 + (1.f - f2) * wxs[t]);
    const float htr = r2 * C2 + (1.f - r2) * xs[t];
    out[base + t * HW] = htl[t] + htr;
  }
}

__global__ __launch_bounds__(256) void conv_gates_kernel(
    const float* __restrict__ x, const float* __restrict__ cw,
    const float* __restrict__ cb, u16* __restrict__ gates) {
  const int sp = blockIdx.x * 256 + threadIdx.x;
  const int oc = blockIdx.y;
  const int bt = blockIdx.z;
  const int b  = bt / T_;
  const int t  = bt - b * T_;
  const int h  = sp >> 7;
  const int wc = sp & (W_ - 1);

  __shared__ float wsh[KVOL];
  for (int i = threadIdx.x; i < KVOL; i += 256) wsh[i] = cw[oc * KVOL + i];
  __syncthreads();

  float acc = cb[oc];
  const float* xb = x + b * (CIN * T_ * HW);
  for (int ci = 0; ci < CIN; ++ci) {
    const float* xc = xb + ci * (T_ * HW);
#pragma unroll
    for (int kd = 0; kd < 3; ++kd) {
      const int tt = t + kd - 1;
      if ((unsigned)tt >= (unsigned)T_) continue;
      const float* xt = xc + tt * HW;
#pragma unroll
      for (int kh = 0; kh < 3; ++kh) {
        const int hh = h + kh - 1;
        if ((unsigned)hh >= (unsigned)H_) continue;
        const float* xr = xt + hh * W_;
        const float* wrp = &wsh[(ci * 3 + kd) * 9 + kh * 3];
        if (wc > 0)      acc += wrp[0] * xr[wc - 1];
        acc += wrp[1] * xr[wc];
        if (wc < W_ - 1) acc += wrp[2] * xr[wc + 1];
      }
    }
  }
  const int g = oc >> 4, c = oc & 15;
  const float av = (g == 0 || g == 5) ? tanh_(acc) : sigmoid_(acc);
  const int off = (((g * B_ + b) * COUT + c) * T_ + t) * HW + sp;
  gates[off] = f2h(av);
}

extern "C" void kernel_launch(void* const* d_in, const int* in_sizes, int n_in,
                              void* d_out, int out_size, void* d_ws,
                              size_t ws_size, hipStream_t stream) {
  (void)in_sizes; (void)n_in; (void)out_size;
  const float* x  = (const float*)d_in[0];
  const float* cw = (const float*)d_in[1];
  const float* cb = (const float*)d_in[2];
  float* out = (float*)d_out;

  const size_t planeElems = (size_t)B_ * COUT * T_ * HW;    // 16,252,928
  const size_t szGatesH = 6 * planeElems * sizeof(u16);     // 195,035,136
  const size_t szX      = (size_t)NPADX * 16 * sizeof(u16); // 36,233,600
  const size_t szW      = (size_t)OC * KP * sizeof(u16);    // 86,016

  char* p = (char*)d_ws;
  if (ws_size >= szX + szW) {
    u16* xh  = (u16*)p;
    u16* wrp = (u16*)(p + szX);
    prep_kernel<<<PADBLK + WBLK, 256, 0, stream>>>(x, cw, xh, wrp);
    const dim3 gfused(W_ / 8, H_, B_);   // 16 x 128 x 2 = 4096 blocks
    conv_sru_fused<<<gfused, 256, 0, stream>>>(xh, wrp, cb, out);
  } else if (ws_size >= szGatesH) {
    u16* gates = (u16*)p;
    const dim3 gdir(HW / 256, OC, B_ * T_);
    conv_gates_kernel<<<gdir, 256, 0, stream>>>(x, cw, cb, gates);
    const int scanBlocks = (B_ * COUT * HW) / 256;
    sru_scan_kernel<<<scanBlocks, 256, 0, stream>>>(gates, out);
  }
}

// Round 4
// 259.088 us; speedup vs baseline: 1.0676x; 1.0676x over previous
//
#include <hip/hip_runtime.h>

#define DEVFN __device__ __forceinline__

typedef __attribute__((ext_vector_type(8))) short short8;
typedef __attribute__((ext_vector_type(4))) float floatx4;
typedef unsigned short u16;
typedef unsigned int u32;

typedef __attribute__((address_space(1))) const void gas_void;
typedef __attribute__((address_space(3))) void las_void;

constexpr int B_   = 2;
constexpr int CIN  = 16;
constexpr int COUT = 16;
constexpr int T_   = 31;
constexpr int H_   = 128;
constexpr int W_   = 128;
constexpr int OC   = 6 * COUT;   // 96
constexpr int HW   = H_ * W_;    // 16384
constexpr int KVOL = CIN * 27;   // 432
constexpr int KP   = 448;        // K padded to 14 * 32

// padded x layout [b][TP][HP][WP][16ci], fp16
constexpr int TP = T_ + 2;       // 33
constexpr int HP = H_ + 2;       // 130
constexpr int WP = W_ + 2;       // 130
constexpr int Sh = WP * 16;      // elems per hh step
constexpr int St = HP * Sh;      // elems per tt step
constexpr int NPAD  = B_ * TP * HP * WP;   // 1,115,400 positions
// +1 zeroed t-slab: fused kernel's pad column t=31 reads padded tt up to 33.
constexpr int NPADX = NPAD + HP * WP;      // 1,132,300
constexpr int PADBLK = (NPADX + 255) / 256;
constexpr int WBLK   = (OC * KP + 255) / 256;

// A-in-LDS: one phase = 7 k-steps, layout [sl(7)][m(6)][quad(4)][n(16)][j(8)]
constexpr int APH = 7 * 6 * 4 * 16 * 8;  // 21504 elems = 43008 B per phase
constexpr int ACHUNK = APH / 8;          // 2688 16B chunks per phase

// gates-in-LDS (aliases A buffer after conv): [g(6)][c(16)][t*8+w],
// c-stride padded 264 -> 268 elems for bank spread.
constexpr int GSTR = 268;
constexpr int GS   = 16 * GSTR;   // 4288
constexpr int GLDS = 6 * GS;      // 25728 elems = 51456 B -> 3 blocks/CU LDS

DEVFN float sigmoid_(float v) { return 1.f / (1.f + __expf(-v)); }
DEVFN float tanh_(float v)    { return 1.f - 2.f / (__expf(2.f * v) + 1.f); }

DEVFN u16 f2h(float v) {  // RNE f32 -> fp16 raw bits
  _Float16 h = (_Float16)v;
  u16 u; __builtin_memcpy(&u, &h, 2); return u;
}
DEVFN float h2f(u16 u) {
  _Float16 h; __builtin_memcpy(&h, &u, 2); return (float)h;
}

// delta (in elems) into padded-x for kernel offset off = kd*9+kh*3+kw;
// off==27 (the K pad) clamps to 26 — A weights there are zero.
DEVFN constexpr int dOff(int off) {
  const int o = (off < 27) ? off : 26;
  return (o / 9) * St + ((o % 9) / 3) * Sh + (o % 3) * 16;
}

// ---------------------------------------------------------------------------
// Prep (merged): blocks [0, PADBLK) do x fp32->fp16 pad/transpose; blocks
// [PADBLK, PADBLK+WBLK) reorder weights to the LDS-ready layout.
// ---------------------------------------------------------------------------
__global__ __launch_bounds__(256) void prep_kernel(const float* __restrict__ x,
                                                   const float* __restrict__ cw,
                                                   u16* __restrict__ xh,
                                                   u16* __restrict__ wr) {
  if (blockIdx.x < PADBLK) {
    const int idx = blockIdx.x * 256 + threadIdx.x;
    if (idx >= NPADX) return;
    int r = idx;
    const int ww = r % WP; r /= WP;
    const int hh = r % HP; r /= HP;
    const int tt = r % TP; const int b = r / TP;
    const bool in_ = (b < B_) & (tt >= 1) & (tt <= T_) & (hh >= 1) &
                     (hh <= H_) & (ww >= 1) & (ww <= W_);
    const int ts = in_ ? tt - 1 : 0, hs = in_ ? hh - 1 : 0,
              ws = in_ ? ww - 1 : 0;
    const int bs = in_ ? b : 0;
    const float* xp = x + ((size_t)bs * CIN * T_ + ts) * HW + hs * W_ + ws;
    u32 ph[8];
#pragma unroll
    for (int ci = 0; ci < 16; ++ci) {
      const float v = in_ ? xp[ci * (T_ * HW)] : 0.f;
      const u16 hu = f2h(v);
      if (ci & 1) ph[ci >> 1] |= ((u32)hu) << 16;
      else        ph[ci >> 1] = hu;
    }
    uint4* dh = (uint4*)(xh + (size_t)idx * 16);
    dh[0] = make_uint4(ph[0], ph[1], ph[2], ph[3]);
    dh[1] = make_uint4(ph[4], ph[5], ph[6], ph[7]);
  } else {
    // weights [oc][ci][27] fp32 -> [s(14)][m(6)][quad(4)][n(16)][j(8)] fp16,
    // oc = m*16+n, k = s*32+quad*8+j.
    const int idx = (blockIdx.x - PADBLK) * 256 + threadIdx.x;
    if (idx >= OC * KP) return;
    const int j    = idx & 7;
    const int n    = (idx >> 3) & 15;
    const int quad = (idx >> 7) & 3;
    const int m    = (idx >> 9) % 6;
    const int s    = idx / 3072;
    const int oc   = m * 16 + n;
    const int k    = s * 32 + quad * 8 + j;
    const int off  = k >> 4, ci = k & 15;
    const float v  = (off < 27) ? cw[oc * KVOL + ci * 27 + off] : 0.f;
    wr[idx] = f2h(v);
  }
}

// B tap load for k-step s into named buffer q (all indices compile-time at
// expansion site -> stays in registers).
#define LOADB(s, q)                                                       \
  do {                                                                    \
    const int d_ = qhalf ? dOff(2 * (s) + 1) : dOff(2 * (s));             \
    q[0] = *(const short8*)(xp0 + d_);                                    \
    q[1] = *(const short8*)(xp1 + d_);                                    \
    q[2] = *(const short8*)(xp2 + d_);                                    \
    q[3] = *(const short8*)(xp3 + d_);                                    \
  } while (0)

// 6 A-fragment ds_read_b128 + 24 MFMA for phase-local step sl using buffer q.
#define MFMAS(sl, q)                                                      \
  do {                                                                    \
    _Pragma("unroll") for (int m_ = 0; m_ < 6; ++m_) {                    \
      const short8 a_ =                                                   \
          *(const short8*)(As + ((sl)*6 + m_) * 512 + quad * 128 + n * 8);\
      _Pragma("unroll") for (int j_ = 0; j_ < 4; ++j_)                    \
          acc[m_][j_] = __builtin_amdgcn_mfma_f32_16x16x32_f16(           \
              a_, q[j_], acc[m_][j_], 0, 0, 0);                           \
    }                                                                     \
  } while (0)

// ---------------------------------------------------------------------------
// Fused conv + bidirectional SRU scan.
// Block = 4 waves = one (b, h, 8w) tile covering ALL t (t-major columns):
//   t = wv*8 + j*2 + (n>>3), w = wbase + (n&7); t==31 is a discarded pad col.
// B-taps from GLOBAL (L1/L2-served; LDS-staging regressed in R3: bank
// conflicts + occupancy). Conv is register-capped at 2 waves/SIMD (96 acc
// regs), so latency is hidden with ILP: explicit depth-2 B prefetch
// pipeline (3 named buffers, hand-unrolled 14-step schedule) and async A
// staging via global_load_lds (no VGPR round-trip). Scan runs split fwd/bwd
// with results parked as fp32 bits in dead gate planes (no regs across
// barriers — R2's spill lesson), then all 256 threads combine.
// ---------------------------------------------------------------------------
__global__ __launch_bounds__(256, 2) void conv_sru_fused(
    const u16* __restrict__ xh, const u16* __restrict__ wr,
    const float* __restrict__ cb, float* __restrict__ out) {
  const int lane = threadIdx.x & 63, wv = threadIdx.x >> 6;
  const int n = lane & 15, quad = lane >> 4;
  const int qhalf = quad >> 1, cihalf = quad & 1;
  const int th = n >> 3, wloc = n & 7;
  const int wbase = blockIdx.x * 8;
  const int h = blockIdx.y;
  const int b = blockIdx.z;

  __shared__ __align__(16) u16 Ls[GLDS];  // 51456 B
  u16* As = Ls;                           // A phase buffer (43008 B)

  // per-thread global base pointers for the 4 column tiles (j -> t += 2)
  const u16 *xp0, *xp1, *xp2, *xp3;
  {
    const int t0 = wv * 8 + th;
    const size_t pb =
        ((size_t)((b * TP + t0) * HP + h) * WP + wbase + wloc) * 16 +
        cihalf * 8;
    xp0 = xh + pb;
    xp1 = xh + pb + (size_t)2 * St;
    xp2 = xh + pb + (size_t)4 * St;
    xp3 = xh + pb + (size_t)6 * St;
  }

  floatx4 acc[6][4];
#pragma unroll
  for (int m = 0; m < 6; ++m)
#pragma unroll
    for (int j = 0; j < 4; ++j) acc[m][j] = (floatx4)(0.f);

  // stage A phase 0 via async global->LDS DMA (dest linear in lane)
#pragma unroll
  for (int it = 0; it < 11; ++it) {
    const int i = it * 256 + (int)threadIdx.x;
    if (i < ACHUNK)
      __builtin_amdgcn_global_load_lds((gas_void*)(wr + (size_t)i * 8),
                                       (las_void*)(As + (size_t)i * 8), 16, 0,
                                       0);
  }

  short8 bq0[4], bq1[4], bq2[4];
  LOADB(0, bq0);          // preload s=0,1 while A DMA is in flight
  LOADB(1, bq1);
  __syncthreads();        // A phase 0 ready (barrier drains vmcnt)

  // phase 0: steps s=0..6, depth-2 prefetch; s=7,8 (phase 1) issued early
  LOADB(2, bq2);  MFMAS(0, bq0);
  LOADB(3, bq0);  MFMAS(1, bq1);
  LOADB(4, bq1);  MFMAS(2, bq2);
  LOADB(5, bq2);  MFMAS(3, bq0);
  LOADB(6, bq0);  MFMAS(4, bq1);
  LOADB(7, bq1);  MFMAS(5, bq2);
  LOADB(8, bq2);  MFMAS(6, bq0);

  __syncthreads();        // phase-0 A consumption complete
#pragma unroll
  for (int it = 0; it < 11; ++it) {
    const int i = it * 256 + (int)threadIdx.x;
    if (i < ACHUNK)
      __builtin_amdgcn_global_load_lds((gas_void*)(wr + APH + (size_t)i * 8),
                                       (las_void*)(As + (size_t)i * 8), 16, 0,
                                       0);
  }
  __syncthreads();        // A phase 1 ready

  // phase 1: steps s=7..13 (phase-local sl = s-7)
  LOADB(9, bq0);   MFMAS(0, bq1);
  LOADB(10, bq1);  MFMAS(1, bq2);
  LOADB(11, bq2);  MFMAS(2, bq0);
  LOADB(12, bq0);  MFMAS(3, bq1);
  LOADB(13, bq1);  MFMAS(4, bq2);
                   MFMAS(5, bq0);
                   MFMAS(6, bq1);

  // epilogue: bias + activation -> gates in LDS (overwrites A staging)
  __syncthreads();
#pragma unroll
  for (int m = 0; m < 6; ++m) {
    const bool isTanh = (m == 0) || (m == 5);
#pragma unroll
    for (int rr = 0; rr < 4; ++rr) {
      const int c = quad * 4 + rr;
      const float bias = cb[m * 16 + c];
#pragma unroll
      for (int j = 0; j < 4; ++j) {
        const int t = wv * 8 + j * 2 + th;
        float v = acc[m][j][rr] + bias;
        v = isTanh ? tanh_(v) : sigmoid_(v);
        Ls[(m * 16 + c) * GSTR + t * 8 + wloc] = f2h(v);
      }
    }
  }
  __syncthreads();

  // ---- split bidirectional scan, no regs live across barriers ----
  const int tid  = threadIdx.x;
  const int half = tid >> 7;        // 0: forward (waves 0-1), 1: backward
  const int ser  = tid & 127;       // (c, w) series
  const int c = ser >> 3, w = ser & 7;
  const int gb = c * GSTR + w;

  if (half == 0) {
    // forward; htl stored as fp32 bits into dead f (plane1) / r (plane3)
    float C = 0.f;
#pragma unroll
    for (int t = 0; t < T_; ++t) {
      const float wx = h2f(Ls[0 * GS + gb + t * 8]);
      const float f  = h2f(Ls[1 * GS + gb + t * 8]);
      const float r  = h2f(Ls[3 * GS + gb + t * 8]);
      const float xv = h2f(Ls[5 * GS + gb + t * 8]);
      C = (t == 0) ? (1.f - f) : (f * C + (1.f - f) * wx);
      const float htl = r * C + (1.f - r) * xv;
      const u32 bits = __float_as_uint(htl);
      Ls[1 * GS + gb + t * 8] = (u16)(bits & 0xffffu);
      Ls[3 * GS + gb + t * 8] = (u16)(bits >> 16);
    }
  } else {
    // backward; htr stored as fp32 bits into dead f2 (plane2) / r2 (plane4)
    float C2 = 0.f;
#pragma unroll
    for (int t = T_ - 1; t >= 0; --t) {
      const float wx = h2f(Ls[0 * GS + gb + t * 8]);
      const float f2 = h2f(Ls[2 * GS + gb + t * 8]);
      const float r2 = h2f(Ls[4 * GS + gb + t * 8]);
      const float xv = h2f(Ls[5 * GS + gb + t * 8]);
      C2 = (t == T_ - 1) ? (1.f - f2) : (f2 * C2 + (1.f - f2) * wx);
      const float htr = r2 * C2 + (1.f - r2) * xv;
      const u32 bits = __float_as_uint(htr);
      Ls[2 * GS + gb + t * 8] = (u16)(bits & 0xffffu);
      Ls[4 * GS + gb + t * 8] = (u16)(bits >> 16);
    }
  }
  __syncthreads();

  // combine + store: all 256 threads, half0 t=0..15, half1 t=16..30
  {
    const int tlo = half ? 16 : 0;
    const int thi = half ? T_ : 16;
    const size_t ob = ((size_t)(b * COUT + c) * T_) * HW + h * W_ + wbase + w;
    for (int t = tlo; t < thi; ++t) {
      const u32 l1 = Ls[1 * GS + gb + t * 8];
      const u32 h1 = Ls[3 * GS + gb + t * 8];
      const u32 l2 = Ls[2 * GS + gb + t * 8];
      const u32 h2 = Ls[4 * GS + gb + t * 8];
      out[ob + (size_t)t * HW] =
          __uint_as_float(l1 | (h1 << 16)) + __uint_as_float(l2 | (h2 << 16));
    }
  }
}

// ---------------------------------------------------------------------------
// Fallback path (only if ws too small for the fused MFMA path).
// ---------------------------------------------------------------------------
__global__ __launch_bounds__(256) void sru_scan_kernel(
    const u16* __restrict__ g, float* __restrict__ out) {
  const int idx  = blockIdx.x * 256 + threadIdx.x;
  const int sp   = idx & (HW - 1);
  const int bc   = idx >> 14;
  const int base = bc * (T_ * HW) + sp;
  const int P    = B_ * COUT * T_ * HW;

  const u16* gWx = g + 0 * P + base;
  const u16* gF  = g + 1 * P + base;
  const u16* gF2 = g + 2 * P + base;
  const u16* gR  = g + 3 * P + base;
  const u16* gR2 = g + 4 * P + base;
  const u16* gX  = g + 5 * P + base;

  float wxs[T_], xs[T_], htl[T_];
  float C = 0.f;
#pragma unroll
  for (int t = 0; t < T_; ++t) {
    const float wx = h2f(gWx[t * HW]);
    const float f  = h2f(gF[t * HW]);
    const float r  = h2f(gR[t * HW]);
    const float xv = h2f(gX[t * HW]);
    wxs[t] = wx;
    xs[t]  = xv;
    C = (t == 0) ? (1.f - f) : (f * C + (1.f - f) * wx);
    htl[t] = r * C + (1.f - r) * xv;
  }
  float C2 = 0.f;
#pragma unroll
  for (int t = T_ - 1; t >= 0; --t) {
    const float f2 = h2f(gF2[t * HW]);
    const float r2 = h2f(gR2[t * HW]);
    C2 = (t == T_ - 1) ? (1.f - f2) : (f2 * C2 + (1.f - f2) * wxs[t]);
    const float htr = r2 * C2 + (1.f - r2) * xs[t];
    out[base + t * HW] = htl[t] + htr;
  }
}

__global__ __launch_bounds__(256) void conv_gates_kernel(
    const float* __restrict__ x, const float* __restrict__ cw,
    const float* __restrict__ cb, u16* __restrict__ gates) {
  const int sp = blockIdx.x * 256 + threadIdx.x;
  const int oc = blockIdx.y;
  const int bt = blockIdx.z;
  const int b  = bt / T_;
  const int t  = bt - b * T_;
  const int h  = sp >> 7;
  const int wc = sp & (W_ - 1);

  __shared__ float wsh[KVOL];
  for (int i = threadIdx.x; i < KVOL; i += 256) wsh[i] = cw[oc * KVOL + i];
  __syncthreads();

  float acc = cb[oc];
  const float* xb = x + b * (CIN * T_ * HW);
  for (int ci = 0; ci < CIN; ++ci) {
    const float* xc = xb + ci * (T_ * HW);
#pragma unroll
    for (int kd = 0; kd < 3; ++kd) {
      const int tt = t + kd - 1;
      if ((unsigned)tt >= (unsigned)T_) continue;
      const float* xt = xc + tt * HW;
#pragma unroll
      for (int kh = 0; kh < 3; ++kh) {
        const int hh = h + kh - 1;
        if ((unsigned)hh >= (unsigned)H_) continue;
        const float* xr = xt + hh * W_;
        const float* wrp = &wsh[(ci * 3 + kd) * 9 + kh * 3];
        if (wc > 0)      acc += wrp[0] * xr[wc - 1];
        acc += wrp[1] * xr[wc];
        if (wc < W_ - 1) acc += wrp[2] * xr[wc + 1];
      }
    }
  }
  const int g = oc >> 4, c = oc & 15;
  const float av = (g == 0 || g == 5) ? tanh_(acc) : sigmoid_(acc);
  const int off = (((g * B_ + b) * COUT + c) * T_ + t) * HW + sp;
  gates[off] = f2h(av);
}

extern "C" void kernel_launch(void* const* d_in, const int* in_sizes, int n_in,
                              void* d_out, int out_size, void* d_ws,
                              size_t ws_size, hipStream_t stream) {
  (void)in_sizes; (void)n_in; (void)out_size;
  const float* x  = (const float*)d_in[0];
  const float* cw = (const float*)d_in[1];
  const float* cb = (const float*)d_in[2];
  float* out = (float*)d_out;

  const size_t planeElems = (size_t)B_ * COUT * T_ * HW;    // 16,252,928
  const size_t szGatesH = 6 * planeElems * sizeof(u16);     // 195,035,136
  const size_t szX      = (size_t)NPADX * 16 * sizeof(u16); // 36,233,600
  const size_t szW      = (size_t)OC * KP * sizeof(u16);    // 86,016

  char* p = (char*)d_ws;
  if (ws_size >= szX + szW) {
    u16* xh  = (u16*)p;
    u16* wrp = (u16*)(p + szX);
    prep_kernel<<<PADBLK + WBLK, 256, 0, stream>>>(x, cw, xh, wrp);
    const dim3 gfused(W_ / 8, H_, B_);   // 16 x 128 x 2 = 4096 blocks
    conv_sru_fused<<<gfused, 256, 0, stream>>>(xh, wrp, cb, out);
  } else if (ws_size >= szGatesH) {
    u16* gates = (u16*)p;
    const dim3 gdir(HW / 256, OC, B_ * T_);
    conv_gates_kernel<<<gdir, 256, 0, stream>>>(x, cw, cb, gates);
    const int scanBlocks = (B_ * COUT * HW) / 256;
    sru_scan_kernel<<<scanBlocks, 256, 0, stream>>>(gates, out);
  }
}

// Round 5
// 253.313 us; speedup vs baseline: 1.0920x; 1.0228x over previous
//
#include <hip/hip_runtime.h>

#define DEVFN __device__ __forceinline__

typedef __attribute__((ext_vector_type(8))) short short8;
typedef __attribute__((ext_vector_type(4))) float floatx4;
typedef unsigned short u16;
typedef unsigned int u32;

constexpr int B_   = 2;
constexpr int CIN  = 16;
constexpr int COUT = 16;
constexpr int T_   = 31;
constexpr int H_   = 128;
constexpr int W_   = 128;
constexpr int OC   = 6 * COUT;   // 96
constexpr int HW   = H_ * W_;    // 16384
constexpr int KVOL = CIN * 27;   // 432
constexpr int KP   = 448;        // K padded to 14 * 32

// padded x layout [b][TP][HP][WP][16ci], fp16
constexpr int TP = T_ + 2;       // 33
constexpr int HP = H_ + 2;       // 130
constexpr int WP = W_ + 2;       // 130
constexpr int Sh = WP * 16;      // elems per hh step
constexpr int St = HP * Sh;      // elems per tt step
constexpr int NPAD  = B_ * TP * HP * WP;   // 1,115,400 positions
// +1 zeroed t-slab: fused kernel's pad column t=31 reads padded tt up to 33.
constexpr int NPADX = NPAD + HP * WP;      // 1,132,300 (even)
constexpr int NP2    = NPADX / 2;          // 566,150 (2 positions/thread)
constexpr int PADBLK = (NP2 + 255) / 256;
constexpr int WBLK   = (OC * KP + 255) / 256;

// A-in-LDS: one phase = 7 k-steps, layout [sl(7)][m(6)][quad(4)][n(16)][j(8)]
constexpr int APH = 7 * 6 * 4 * 16 * 8;  // 21504 elems = 43008 B per phase

// gates-in-LDS (aliased over A buffer after conv): [g(6)][c(16)][t*8+w],
// c-stride padded 264 -> 268 elems so the 4 quads land on distinct banks.
constexpr int GSTR = 268;
constexpr int GS   = 16 * GSTR;   // 4288
constexpr int GLDS = 6 * GS;      // 25728 elems = 51456 B -> 3 blocks/CU LDS

DEVFN float sigmoid_(float v) { return 1.f / (1.f + __expf(-v)); }
DEVFN float tanh_(float v)    { return 1.f - 2.f / (__expf(2.f * v) + 1.f); }

DEVFN u16 f2h(float v) {  // RNE f32 -> fp16 raw bits
  _Float16 h = (_Float16)v;
  u16 u; __builtin_memcpy(&u, &h, 2); return u;
}
DEVFN float h2f(u16 u) {
  _Float16 h; __builtin_memcpy(&h, &u, 2); return (float)h;
}

// delta (in elems) into padded-x for kernel offset off = kd*9+kh*3+kw;
// off==27 (the K pad) clamps to 26 — A weights there are zero.
DEVFN constexpr int dOff(int off) {
  const int o = (off < 27) ? off : 26;
  return (o / 9) * St + ((o % 9) / 3) * Sh + (o % 3) * 16;
}

// ---------------------------------------------------------------------------
// Prep (merged): blocks [0, PADBLK) do x fp32->fp16 pad/transpose with TWO
// consecutive ww positions per thread (halved index decode, 64 B stores);
// blocks [PADBLK, PADBLK+WBLK) reorder weights to the LDS-ready layout.
// ---------------------------------------------------------------------------
__global__ __launch_bounds__(256) void prep_kernel(const float* __restrict__ x,
                                                   const float* __restrict__ cw,
                                                   u16* __restrict__ xh,
                                                   u16* __restrict__ wr) {
  if (blockIdx.x < PADBLK) {
    const int idx2 = blockIdx.x * 256 + threadIdx.x;
    if (idx2 >= NP2) return;
    int r = idx2;
    const int k  = r % (WP / 2); r /= (WP / 2);
    const int hh = r % HP; r /= HP;
    const int tt = r % TP; const int b = r / TP;
    const int ww0 = 2 * k;                       // even; ww1 = ww0+1
    const bool bin = (b < B_) & (tt >= 1) & (tt <= T_) & (hh >= 1) &
                     (hh <= H_);
    const bool in0 = bin & (ww0 >= 1) & (ww0 <= W_);
    const bool in1 = bin & (ww0 + 1 <= W_);
    const int ts = bin ? tt - 1 : 0, hs = bin ? hh - 1 : 0;
    const int bs = (b < B_) ? b : 0;
    const float* xp = x + ((size_t)bs * CIN * T_ + ts) * HW + hs * W_;
    u32 ph[16];
#pragma unroll
    for (int ci = 0; ci < 16; ++ci) {
      const float v0 = in0 ? xp[ci * (T_ * HW) + ww0 - 1] : 0.f;
      const float v1 = in1 ? xp[ci * (T_ * HW) + ww0] : 0.f;
      const u16 h0 = f2h(v0), h1 = f2h(v1);
      if (ci & 1) {
        ph[ci >> 1]       |= ((u32)h0) << 16;
        ph[8 + (ci >> 1)] |= ((u32)h1) << 16;
      } else {
        ph[ci >> 1]       = h0;
        ph[8 + (ci >> 1)] = h1;
      }
    }
    uint4* dh = (uint4*)(xh + (size_t)idx2 * 32);
    dh[0] = make_uint4(ph[0], ph[1], ph[2], ph[3]);
    dh[1] = make_uint4(ph[4], ph[5], ph[6], ph[7]);
    dh[2] = make_uint4(ph[8], ph[9], ph[10], ph[11]);
    dh[3] = make_uint4(ph[12], ph[13], ph[14], ph[15]);
  } else {
    // weights [oc][ci][27] fp32 -> [s(14)][m(6)][quad(4)][n(16)][j(8)] fp16,
    // oc = m*16+n, k = s*32+quad*8+j.
    const int idx = (blockIdx.x - PADBLK) * 256 + threadIdx.x;
    if (idx >= OC * KP) return;
    const int j    = idx & 7;
    const int n    = (idx >> 3) & 15;
    const int quad = (idx >> 7) & 3;
    const int m    = (idx >> 9) % 6;
    const int s    = idx / 3072;
    const int oc   = m * 16 + n;
    const int kk   = s * 32 + quad * 8 + j;
    const int off  = kk >> 4, ci = kk & 15;
    const float v  = (off < 27) ? cw[oc * KVOL + ci * 27 + off] : 0.f;
    wr[idx] = f2h(v);
  }
}

// ---------------------------------------------------------------------------
// One k-phase (7 steps), PH compile-time so dOff folds to immediates.
// Single fp16 pass: 4 B-loads + 24 MFMA per step. xp0..xp3 are the
// per-thread base pointers of the wave's 4 column-tiles (8w x 2t each).
// Compiler-scheduled (R4's hand pipeline regressed 155->190 us — do not
// re-introduce explicit prefetch buffers here).
// ---------------------------------------------------------------------------
template <int PH>
DEVFN void kphase(const u16* __restrict__ xp0, const u16* __restrict__ xp1,
                  const u16* __restrict__ xp2, const u16* __restrict__ xp3,
                  const u16* As, int n, int quad, int qhalf,
                  floatx4 (&acc)[6][4]) {
#pragma unroll
  for (int sl = 0; sl < 7; ++sl) {
    const int s = PH * 7 + sl;
    const int d = qhalf ? dOff(2 * s + 1) : dOff(2 * s);
    short8 bh[4];
    bh[0] = *(const short8*)(xp0 + d);
    bh[1] = *(const short8*)(xp1 + d);
    bh[2] = *(const short8*)(xp2 + d);
    bh[3] = *(const short8*)(xp3 + d);
#pragma unroll
    for (int m = 0; m < 6; ++m) {
      const short8 a =
          *(const short8*)(As + (sl * 6 + m) * 512 + quad * 128 + n * 8);
#pragma unroll
      for (int j = 0; j < 4; ++j)
        acc[m][j] =
            __builtin_amdgcn_mfma_f32_16x16x32_f16(a, bh[j], acc[m][j], 0, 0, 0);
    }
  }
}

// ---------------------------------------------------------------------------
// Fused conv + bidirectional SRU scan — R1 structure (measured best, 155 us):
// Block = 4 waves = one (b, h, 8w) tile covering ALL t (t-major columns):
//   t = wv*8 + j*2 + (n>>3), w = wbase + (n&7); t==31 is a discarded pad col.
// B-taps from GLOBAL (L2-served); A staged to LDS via reg round-trip in 2
// phases; serial split-by-direction scan REVERTED to R1's form: waves 0-1
// run the full fwd+bwd serial scan per (c,w) series with wx/x/htl in
// registers (no barrier crossing), waves 2-3 idle. R2/R3/R4 alternatives
// (reg-split, parked-split) all measured slower.
// ---------------------------------------------------------------------------
__global__ __launch_bounds__(256, 3) void conv_sru_fused(
    const u16* __restrict__ xh, const u16* __restrict__ wr,
    const float* __restrict__ cb, float* __restrict__ out) {
  const int lane = threadIdx.x & 63, wv = threadIdx.x >> 6;
  const int n = lane & 15, quad = lane >> 4;
  const int qhalf = quad >> 1, cihalf = quad & 1;
  const int th = n >> 3, wloc = n & 7;
  const int wbase = blockIdx.x * 8;
  const int h = blockIdx.y;
  const int b = blockIdx.z;

  __shared__ __align__(16) u16 As[GLDS];  // 51456 B (A phases alias gates)

  // per-thread base pointers for the 4 column tiles (j -> t += 2)
  const u16 *xp0, *xp1, *xp2, *xp3;
  {
    const int t0 = wv * 8 + th;
    const size_t pb =
        ((size_t)((b * TP + t0) * HP + h) * WP + wbase + wloc) * 16 +
        cihalf * 8;
    xp0 = xh + pb;
    xp1 = xh + pb + (size_t)2 * St;
    xp2 = xh + pb + (size_t)4 * St;
    xp3 = xh + pb + (size_t)6 * St;
  }

  floatx4 acc[6][4];
#pragma unroll
  for (int m = 0; m < 6; ++m)
#pragma unroll
    for (int j = 0; j < 4; ++j) acc[m][j] = (floatx4)(0.f);

  // phase 0: stage A[s=0..6], compute
  for (int i = threadIdx.x; i < APH / 8; i += 256)
    ((uint4*)As)[i] = ((const uint4*)wr)[i];
  __syncthreads();
  kphase<0>(xp0, xp1, xp2, xp3, As, n, quad, qhalf, acc);

  // phase 1: restage A[s=7..13], compute
  __syncthreads();
  for (int i = threadIdx.x; i < APH / 8; i += 256)
    ((uint4*)As)[i] = ((const uint4*)(wr + APH))[i];
  __syncthreads();
  kphase<1>(xp0, xp1, xp2, xp3, As, n, quad, qhalf, acc);

  // epilogue: bias + activation -> gates in LDS (overwrites A staging)
  __syncthreads();
#pragma unroll
  for (int m = 0; m < 6; ++m) {
    const bool isTanh = (m == 0) || (m == 5);
#pragma unroll
    for (int rr = 0; rr < 4; ++rr) {
      const int c = quad * 4 + rr;
      const float bias = cb[m * 16 + c];
#pragma unroll
      for (int j = 0; j < 4; ++j) {
        const int t = wv * 8 + j * 2 + th;
        float v = acc[m][j][rr] + bias;
        v = isTanh ? tanh_(v) : sigmoid_(v);
        As[(m * 16 + c) * GSTR + t * 8 + wloc] = f2h(v);
      }
    }
  }
  __syncthreads();

  // bidirectional scan: 128 threads, one (c, w) series each (T_=31 steps).
  if (threadIdx.x < 128) {
    const int c = threadIdx.x >> 3;
    const int w = threadIdx.x & 7;
    const int gb = c * GSTR + w;
    float htl[T_];
    float C = 0.f;
#pragma unroll
    for (int t = 0; t < T_; ++t) {
      const float wx = h2f(As[0 * GS + gb + t * 8]);
      const float f  = h2f(As[1 * GS + gb + t * 8]);
      const float r  = h2f(As[3 * GS + gb + t * 8]);
      const float xv = h2f(As[5 * GS + gb + t * 8]);
      C = (t == 0) ? (1.f - f) : (f * C + (1.f - f) * wx);
      htl[t] = r * C + (1.f - r) * xv;
    }
    const size_t ob =
        ((size_t)(b * COUT + c) * T_) * HW + h * W_ + wbase + w;
    float C2 = 0.f;
#pragma unroll
    for (int t = T_ - 1; t >= 0; --t) {
      const float wx = h2f(As[0 * GS + gb + t * 8]);
      const float f2 = h2f(As[2 * GS + gb + t * 8]);
      const float r2 = h2f(As[4 * GS + gb + t * 8]);
      const float xv = h2f(As[5 * GS + gb + t * 8]);
      C2 = (t == T_ - 1) ? (1.f - f2) : (f2 * C2 + (1.f - f2) * wx);
      const float htr = r2 * C2 + (1.f - r2) * xv;
      out[ob + (size_t)t * HW] = htl[t] + htr;
    }
  }
}

// ---------------------------------------------------------------------------
// Fallback path (only if ws too small for the fused MFMA path).
// ---------------------------------------------------------------------------
__global__ __launch_bounds__(256) void sru_scan_kernel(
    const u16* __restrict__ g, float* __restrict__ out) {
  const int idx  = blockIdx.x * 256 + threadIdx.x;
  const int sp   = idx & (HW - 1);
  const int bc   = idx >> 14;
  const int base = bc * (T_ * HW) + sp;
  const int P    = B_ * COUT * T_ * HW;

  const u16* gWx = g + 0 * P + base;
  const u16* gF  = g + 1 * P + base;
  const u16* gF2 = g + 2 * P + base;
  const u16* gR  = g + 3 * P + base;
  const u16* gR2 = g + 4 * P + base;
  const u16* gX  = g + 5 * P + base;

  float wxs[T_], xs[T_], htl[T_];
  float C = 0.f;
#pragma unroll
  for (int t = 0; t < T_; ++t) {
    const float wx = h2f(gWx[t * HW]);
    const float f  = h2f(gF[t * HW]);
    const float r  = h2f(gR[t * HW]);
    const float xv = h2f(gX[t * HW]);
    wxs[t] = wx;
    xs[t]  = xv;
    C = (t == 0) ? (1.f - f) : (f * C + (1.f - f) * wx);
    htl[t] = r * C + (1.f - r) * xv;
  }
  float C2 = 0.f;
#pragma unroll
  for (int t = T_ - 1; t >= 0; --t) {
    const float f2 = h2f(gF2[t * HW]);
    const float r2 = h2f(gR2[t * HW]);
    C2 = (t == T_ - 1) ? (1.f - f2) : (f2 * C2 + (1.f - f2) * wxs[t]);
    const float htr = r2 * C2 + (1.f - r2) * xs[t];
    out[base + t * HW] = htl[t] + htr;
  }
}

__global__ __launch_bounds__(256) void conv_gates_kernel(
    const float* __restrict__ x, const float* __restrict__ cw,
    const float* __restrict__ cb, u16* __restrict__ gates) {
  const int sp = blockIdx.x * 256 + threadIdx.x;
  const int oc = blockIdx.y;
  const int bt = blockIdx.z;
  const int b  = bt / T_;
  const int t  = bt - b * T_;
  const int h  = sp >> 7;
  const int wc = sp & (W_ - 1);

  __shared__ float wsh[KVOL];
  for (int i = threadIdx.x; i < KVOL; i += 256) wsh[i] = cw[oc * KVOL + i];
  __syncthreads();

  float acc = cb[oc];
  const float* xb = x + b * (CIN * T_ * HW);
  for (int ci = 0; ci < CIN; ++ci) {
    const float* xc = xb + ci * (T_ * HW);
#pragma unroll
    for (int kd = 0; kd < 3; ++kd) {
      const int tt = t + kd - 1;
      if ((unsigned)tt >= (unsigned)T_) continue;
      const float* xt = xc + tt * HW;
#pragma unroll
      for (int kh = 0; kh < 3; ++kh) {
        const int hh = h + kh - 1;
        if ((unsigned)hh >= (unsigned)H_) continue;
        const float* xr = xt + hh * W_;
        const float* wrp = &wsh[(ci * 3 + kd) * 9 + kh * 3];
        if (wc > 0)      acc += wrp[0] * xr[wc - 1];
        acc += wrp[1] * xr[wc];
        if (wc < W_ - 1) acc += wrp[2] * xr[wc + 1];
      }
    }
  }
  const int g = oc >> 4, c = oc & 15;
  const float av = (g == 0 || g == 5) ? tanh_(acc) : sigmoid_(acc);
  const int off = (((g * B_ + b) * COUT + c) * T_ + t) * HW + sp;
  gates[off] = f2h(av);
}

extern "C" void kernel_launch(void* const* d_in, const int* in_sizes, int n_in,
                              void* d_out, int out_size, void* d_ws,
                              size_t ws_size, hipStream_t stream) {
  (void)in_sizes; (void)n_in; (void)out_size;
  const float* x  = (const float*)d_in[0];
  const float* cw = (const float*)d_in[1];
  const float* cb = (const float*)d_in[2];
  float* out = (float*)d_out;

  const size_t planeElems = (size_t)B_ * COUT * T_ * HW;    // 16,252,928
  const size_t szGatesH = 6 * planeElems * sizeof(u16);     // 195,035,136
  const size_t szX      = (size_t)NPADX * 16 * sizeof(u16); // 36,233,600
  const size_t szW      = (size_t)OC * KP * sizeof(u16);    // 86,016

  char* p = (char*)d_ws;
  if (ws_size >= szX + szW) {
    u16* xh  = (u16*)p;
    u16* wrp = (u16*)(p + szX);
    prep_kernel<<<PADBLK + WBLK, 256, 0, stream>>>(x, cw, xh, wrp);
    const dim3 gfused(W_ / 8, H_, B_);   // 16 x 128 x 2 = 4096 blocks
    conv_sru_fused<<<gfused, 256, 0, stream>>>(xh, wrp, cb, out);
  } else if (ws_size >= szGatesH) {
    u16* gates = (u16*)p;
    const dim3 gdir(HW / 256, OC, B_ * T_);
    conv_gates_kernel<<<gdir, 256, 0, stream>>>(x, cw, cb, gates);
    const int scanBlocks = (B_ * COUT * HW) / 256;
    sru_scan_kernel<<<scanBlocks, 256, 0, stream>>>(gates, out);
  }
}